// Round 8
// baseline (600.147 us; speedup 1.0000x reference)
//
#include <hip/hip_runtime.h>

typedef unsigned short u16;
typedef __attribute__((ext_vector_type(4))) u16 u16x4;
typedef __attribute__((ext_vector_type(8))) u16 u16x8;
typedef __attribute__((ext_vector_type(8))) short bf16x8;
typedef __attribute__((ext_vector_type(4))) float f32x4;

// Problem constants
#define BB 2
#define TT 2048
#define DD 768
#define NH 12
#define HDIM 64
#define NQKV 2304   // 3*DD
#define MM 4096     // BB*TT

__device__ __forceinline__ u16 f2bf(float f) {
  unsigned u = __float_as_uint(f);
  u += 0x7fffu + ((u >> 16) & 1u);
  return (u16)(u >> 16);
}
__device__ __forceinline__ float bf2f(u16 s) {
  return __uint_as_float(((unsigned)s) << 16);
}
__device__ __forceinline__ void async_load16(const void* g, void* l) {
  __builtin_amdgcn_global_load_lds((const __attribute__((address_space(1))) void*)g,
                                   (__attribute__((address_space(3))) void*)l, 16, 0, 0);
}

// ---------------- merged prep: castx | weight transpose+cast | gidx/bias ----------------
// blocks [0,3072): cast x; [3072,5376): transpose W (576 per matrix); 5376: misc
__global__ __launch_bounds__(256) void prep_all(const float* __restrict__ x,
                                                const float* __restrict__ Wq, const float* __restrict__ Wk,
                                                const float* __restrict__ Wv, const float* __restrict__ Wo,
                                                const int* __restrict__ gm,
                                                const float* __restrict__ bq, const float* __restrict__ bk,
                                                const float* __restrict__ bv,
                                                u16* __restrict__ xb, u16* __restrict__ wqkvT,
                                                u16* __restrict__ woT,
                                                int* __restrict__ gidx, float* __restrict__ biasqkv) {
  __shared__ float tile[32][33];
  const int bid = blockIdx.x;
  const int tid = threadIdx.x;
  if (bid < 3072) {                                  // ---- cast x, one float4/thread ----
    int i = bid * 256 + tid;
    float4 v = ((const float4*)x)[i];
    u16x4 o = { f2bf(v.x), f2bf(v.y), f2bf(v.z), f2bf(v.w) };
    ((u16x4*)xb)[i] = o;
  } else if (bid < 5376) {                           // ---- W(K,N) -> WT(N,K) bf16 ----
    int r = bid - 3072;
    int z = r / 576; r %= 576;
    int kx = r % 24, ny = r / 24;
    const float* W = (z == 0) ? Wq : (z == 1) ? Wk : (z == 2) ? Wv : Wo;
    u16* dst = (z < 3) ? (wqkvT + (size_t)z * DD * DD) : woT;
    int k0 = kx * 32, n0 = ny * 32;
    int tx = tid & 31, ty = tid >> 5;                // 32 x 8
#pragma unroll
    for (int j = 0; j < 4; ++j)
      tile[ty + j * 8][tx] = W[(size_t)(k0 + ty + j * 8) * DD + n0 + tx];
    __syncthreads();
#pragma unroll
    for (int j = 0; j < 4; ++j)
      dst[(size_t)(n0 + ty + j * 8) * DD + k0 + tx] = f2bf(tile[tx][ty + j * 8]);
  } else {                                           // ---- gidx + fused qkv bias ----
    for (int n = tid; n < NQKV; n += 256)
      biasqkv[n] = (n < 768) ? bq[n] : (n < 1536) ? bk[n - 768] : bv[n - 1536];
    if (tid < 64) {                                  // wave 0 only (program-order safe)
      int lane = tid;
      if (lane < 32) gidx[lane] = 0;
      int base = 0;
      for (int c0 = 0; c0 < TT; c0 += 64) {
        int mval = gm[c0 + lane];
        unsigned long long bal = __ballot(mval != 0);
        int pre = __popcll(bal & ((1ull << lane) - 1ull));
        if (mval && (base + pre) < 32) gidx[base + pre] = c0 + lane;
        base += __popcll(bal);
        if (base >= 32) break;
      }
    }
  }
}

// ---------------- bf16 MFMA GEMM: C(M,N) = A(M,K) * BT(N,K)^T + bias ----------------
template <int BM, bool OUTBF>
__global__ __launch_bounds__(256) void gemm_bt(const u16* __restrict__ A, const u16* __restrict__ BT,
                                               const float* __restrict__ bias, void* __restrict__ Cv,
                                               int Ndim, int Kd) {
  constexpr int NJ = (BM == 128) ? 4 : 2;            // 16-col tiles per wave
  constexpr int ACH = BM / 32;                       // A staging chunks per wave
  __shared__ __attribute__((aligned(16))) u16 As[BM * 64];
  __shared__ __attribute__((aligned(16))) u16 Bs[128 * 64];
  const int tid = threadIdx.x;
  const int wave = tid >> 6, lane = tid & 63;
  const int m0 = blockIdx.x * BM, n0 = blockIdx.y * 128;
  const int wm = (BM == 128) ? ((wave & 1) << 6) : 0;
  const int wn = (BM == 128) ? ((wave >> 1) << 6) : (wave << 5);
  const int lr = lane & 15, lk = lane >> 4;
  const int srow_b = lane >> 3;          // 0..7
  const int scol = (lane & 7) * 8;       // ushort offset within 128B row slice

  f32x4 acc[4][NJ] = {};

  const int kIters = Kd >> 6;
  for (int kt = 0; kt < kIters; ++kt) {
#pragma unroll
    for (int cc = 0; cc < ACH; ++cc) {
      int c = wave * ACH + cc;
      int srow = c * 8 + srow_b;
      async_load16(A + (size_t)(m0 + srow) * Kd + (kt << 6) + scol, (void*)(As + c * 512));
    }
#pragma unroll
    for (int cc = 0; cc < 4; ++cc) {
      int c = wave * 4 + cc;
      int srow = c * 8 + srow_b;
      async_load16(BT + (size_t)(n0 + srow) * Kd + (kt << 6) + scol, (void*)(Bs + c * 512));
    }
    __syncthreads();
#pragma unroll
    for (int kc = 0; kc < 2; ++kc) {
      bf16x8 af[4], bfr[NJ];
#pragma unroll
      for (int i = 0; i < 4; ++i)
        af[i] = *(const bf16x8*)(As + (wm + i * 16 + lr) * 64 + kc * 32 + lk * 8);
#pragma unroll
      for (int j = 0; j < NJ; ++j)
        bfr[j] = *(const bf16x8*)(Bs + (wn + j * 16 + lr) * 64 + kc * 32 + lk * 8);
#pragma unroll
      for (int i = 0; i < 4; ++i)
#pragma unroll
        for (int j = 0; j < NJ; ++j)
          acc[i][j] = __builtin_amdgcn_mfma_f32_16x16x32_bf16(af[i], bfr[j], acc[i][j], 0, 0, 0);
    }
    __syncthreads();
  }

#pragma unroll
  for (int i = 0; i < 4; ++i) {
    const int row = m0 + wm + i * 16 + lk * 4;
#pragma unroll
    for (int j = 0; j < NJ; ++j) {
      const int col = n0 + wn + j * 16 + lr;
      const float bs = bias[col];
#pragma unroll
      for (int r = 0; r < 4; ++r) {
        const float val = acc[i][j][r] + bs;
        if (OUTBF) ((u16*)Cv)[(size_t)(row + r) * Ndim + col] = f2bf(val);
        else       ((float*)Cv)[(size_t)(row + r) * Ndim + col] = val;
      }
    }
  }
}

// ---------------- attention: R7 structure + DIAGNOSTIC x4 repeat of phases 2-3 ----------------
// dur_delta = 3 x (phase2+phase3). cacc accumulates 4 identical passes; epilogue scales by 0.25.
__global__ __launch_bounds__(256) void attn_kernel(const u16* __restrict__ qb,
                                                   const int* __restrict__ gidx,
                                                   u16* __restrict__ ctxb,
                                                   float* __restrict__ fattn) {
  __shared__ __attribute__((aligned(16))) u16 Kl[96 * 72];
  __shared__ __attribute__((aligned(16))) u16 Kg[32 * 72];
  __shared__ __attribute__((aligned(16))) u16 Vl[96 * 72];
  __shared__ __attribute__((aligned(16))) u16 Vg[32 * 72];
  __shared__ __attribute__((aligned(16))) float probs[64 * 68];
  __shared__ int gidxs[32];

  const int tid = threadIdx.x;
  const int blk = blockIdx.x;
  const int chunk = blk & 31;
  const int h = (blk >> 5) % NH;
  const int b = blk / 384;
  const int t0 = chunk << 6;

  // ---- phase 1: stage bf16 K/V (once) ----
  {
    const int r = tid >> 3;                // 0..31 rows per pass
    const int c8 = (tid & 7) << 3;         // 8 bf16 per lane
#pragma unroll
    for (int it = 0; it < 3; ++it) {
      int rr = it * 32 + r;
      int t = t0 - 16 + rr;
      t = t < 0 ? 0 : (t > TT - 1 ? TT - 1 : t);
      const u16* src = qb + (size_t)(b * TT + t) * NQKV + h * HDIM + c8;
      *(u16x8*)(Kl + rr * 72 + c8) = *(const u16x8*)(src + 768);
      *(u16x8*)(Vl + rr * 72 + c8) = *(const u16x8*)(src + 1536);
    }
    {
      int t = gidx[r];
      const u16* src = qb + (size_t)(b * TT + t) * NQKV + h * HDIM + c8;
      *(u16x8*)(Kg + r * 72 + c8) = *(const u16x8*)(src + 768);
      *(u16x8*)(Vg + r * 72 + c8) = *(const u16x8*)(src + 1536);
    }
    if (tid < 32) gidxs[tid] = gidx[tid];
  }
  __syncthreads();

  const int tl = tid >> 2, sub = tid & 3;
  const int t = t0 + tl;
  const u16* qp = qb + (size_t)(b * TT + t) * NQKV + h * HDIM;
  float qv[64];
#pragma unroll
  for (int i = 0; i < 8; ++i) {
    u16x8 qq = *(const u16x8*)(qp + i * 8);
#pragma unroll
    for (int e = 0; e < 8; ++e) qv[i * 8 + e] = bf2f(qq[e]);
  }

  float cacc[16];
#pragma unroll
  for (int i = 0; i < 16; ++i) cacc[i] = 0.f;

#pragma unroll 1
  for (int rep = 0; rep < 4; ++rep) {
    // ---- phase 2: scores + softmax ----
    float sc[17];
    float mmax = -__builtin_inff();
#pragma unroll
    for (int i = 0; i < 17; ++i) {
      const int s = sub + (i << 2);
      const u16* kp;
      bool valid;
      if (s < 33) { kp = Kl + (tl + s) * 72; int j = t - 16 + s; valid = (j >= 0) && (j < TT); }
      else if (s < 65) { kp = Kg + (s - 33) * 72; valid = true; }
      else { kp = Kg; valid = false; }
      float d = 0.f;
#pragma unroll
      for (int i2 = 0; i2 < 8; ++i2) {
        u16x8 kv = *(const u16x8*)(kp + i2 * 8);
#pragma unroll
        for (int e = 0; e < 8; ++e) d += qv[i2 * 8 + e] * bf2f(kv[e]);
      }
      sc[i] = valid ? d * 0.125f : -__builtin_inff();
      mmax = fmaxf(mmax, sc[i]);
    }
    mmax = fmaxf(mmax, __shfl_xor(mmax, 1));
    mmax = fmaxf(mmax, __shfl_xor(mmax, 2));
    float sum = 0.f;
#pragma unroll
    for (int i = 0; i < 17; ++i) { sc[i] = __expf(sc[i] - mmax); sum += sc[i]; }
    sum += __shfl_xor(sum, 1);
    sum += __shfl_xor(sum, 2);
    const float inv = 1.0f / sum;
#pragma unroll
    for (int i = 0; i < 17; ++i) {
      const int s = sub + (i << 2);
      sc[i] *= inv;
      if (s < 65) probs[tl * 68 + s] = sc[i];
    }
    __syncthreads();

    // ---- phase 3: accumulate ctx (4 identical passes -> x4) ----
#pragma unroll 1
    for (int k = 0; k < 65; ++k) {
      const float pv = probs[tl * 68 + k];
      const u16* vp = (k < 33) ? (Vl + (tl + k) * 72) : (Vg + (k - 33) * 72);
      const u16* vq = vp + (sub << 4);
      u16x8 v0 = *(const u16x8*)(vq);
      u16x8 v1 = *(const u16x8*)(vq + 8);
#pragma unroll
      for (int e = 0; e < 8; ++e) { cacc[e] += pv * bf2f(v0[e]); cacc[8 + e] += pv * bf2f(v1[e]); }
    }
    __syncthreads();   // protect probs reads before next rep rewrites
  }

  {
    u16x8 cb0, cb1;
#pragma unroll
    for (int e = 0; e < 8; ++e) { cb0[e] = f2bf(cacc[e] * 0.25f); cb1[e] = f2bf(cacc[8 + e] * 0.25f); }
    u16* dst = ctxb + (size_t)(b * TT + t) * DD + h * HDIM + (sub << 4);
    *(u16x8*)dst = cb0;
    *(u16x8*)(dst + 8) = cb1;
  }

  // ---- phase 4a: stream-write 64 fattn rows, band embedded, zeros elsewhere ----
  float* fbase = fattn + ((size_t)(b * NH + h) * TT + t0) * TT;
#pragma unroll 1
  for (int it = 0; it < 128; ++it) {
    int f = it * 256 + tid;
    int rl = f >> 9;                 // row 0..63 (2 waves per row)
    int c4 = (f & 511) << 2;         // col 0..2044
    int trow = t0 + rl;
    float4 v = make_float4(0.f, 0.f, 0.f, 0.f);
    int kk = c4 - trow + 16;         // band coord of first element
    if (kk >= -3 && kk < 33) {
      const float* pr = probs + rl * 68;
      float* vp = &v.x;
#pragma unroll
      for (int e = 0; e < 4; ++e) {
        int k2 = kk + e;
        if ((unsigned)k2 < 33u) vp[e] = pr[k2];
      }
    }
    *(float4*)(fbase + (size_t)rl * TT + c4) = v;
  }
  __syncthreads();                    // drain 4a stores before 4b overwrites

  // ---- phase 4b: overwrite the 32 global columns (.set overrides band) ----
  {
    int rl = tid >> 2, g0 = (tid & 3) << 3;
    const float* pr = probs + rl * 68 + 33;
    float* frow = fbase + (size_t)rl * TT;
#pragma unroll
    for (int e = 0; e < 8; ++e) frow[gidxs[g0 + e]] = pr[g0 + e];
  }
}

extern "C" void kernel_launch(void* const* d_in, const int* in_sizes, int n_in,
                              void* d_out, int out_size, void* d_ws, size_t ws_size,
                              hipStream_t stream) {
  const float* x  = (const float*)d_in[0];
  const int* gm   = (const int*)d_in[1];
  const float* Wq = (const float*)d_in[2];
  const float* bq = (const float*)d_in[3];
  const float* Wk = (const float*)d_in[4];
  const float* bk = (const float*)d_in[5];
  const float* Wv = (const float*)d_in[6];
  const float* bv = (const float*)d_in[7];
  const float* Wo = (const float*)d_in[8];
  const float* bo = (const float*)d_in[9];

  float* out = (float*)d_out;
  float* fattn = out + (size_t)BB * TT * DD;

  char* p = (char*)d_ws;
  u16* xb      = (u16*)p;  p += (size_t)MM * DD * 2;        // 6291456
  u16* wqkvT   = (u16*)p;  p += (size_t)NQKV * DD * 2;      // 3538944
  u16* woT     = (u16*)p;  p += (size_t)DD * DD * 2;        // 1179648
  float* biasq = (float*)p; p += (size_t)NQKV * 4;          // 9216
  int* gidx    = (int*)p;  p += 128;
  u16* qkvb    = (u16*)p;  p += (size_t)MM * NQKV * 2;      // 18874368 (bf16 qkv)
  u16* ctxb    = (u16*)p;  p += (size_t)MM * DD * 2;        // 6291456

  prep_all<<<5377, 256, 0, stream>>>(x, Wq, Wk, Wv, Wo, gm, bq, bk, bv,
                                     xb, wqkvT, woT, gidx, biasq);
  gemm_bt<128, true><<<dim3(MM / 128, NQKV / 128), 256, 0, stream>>>(xb, wqkvT, biasq, qkvb, NQKV, DD);
  attn_kernel<<<BB * NH * (TT / 64), 256, 0, stream>>>(qkvb, gidx, ctxb, fattn);
  gemm_bt<64, false><<<dim3(MM / 64, DD / 128), 256, 0, stream>>>(ctxb, woT, bo, out, DD, DD);
}

// Round 9
// 538.834 us; speedup vs baseline: 1.1138x; 1.1138x over previous
//
#include <hip/hip_runtime.h>

typedef unsigned short u16;
typedef __attribute__((ext_vector_type(4))) u16 u16x4;
typedef __attribute__((ext_vector_type(8))) u16 u16x8;
typedef __attribute__((ext_vector_type(8))) short bf16x8;
typedef __attribute__((ext_vector_type(4))) float f32x4;

// Problem constants
#define BB 2
#define TT 2048
#define DD 768
#define NH 12
#define HDIM 64
#define NQKV 2304   // 3*DD
#define MM 4096     // BB*TT

__device__ __forceinline__ u16 f2bf(float f) {
  unsigned u = __float_as_uint(f);
  u += 0x7fffu + ((u >> 16) & 1u);
  return (u16)(u >> 16);
}
__device__ __forceinline__ float bf2f(u16 s) {
  return __uint_as_float(((unsigned)s) << 16);
}
__device__ __forceinline__ void async_load16(const void* g, void* l) {
  __builtin_amdgcn_global_load_lds((const __attribute__((address_space(1))) void*)g,
                                   (__attribute__((address_space(3))) void*)l, 16, 0, 0);
}

// ---------------- merged prep: castx | weight transpose+cast | gidx/bias ----------------
__global__ __launch_bounds__(256) void prep_all(const float* __restrict__ x,
                                                const float* __restrict__ Wq, const float* __restrict__ Wk,
                                                const float* __restrict__ Wv, const float* __restrict__ Wo,
                                                const int* __restrict__ gm,
                                                const float* __restrict__ bq, const float* __restrict__ bk,
                                                const float* __restrict__ bv,
                                                u16* __restrict__ xb, u16* __restrict__ wqkvT,
                                                u16* __restrict__ woT,
                                                int* __restrict__ gidx, float* __restrict__ biasqkv) {
  __shared__ float tile[32][33];
  const int bid = blockIdx.x;
  const int tid = threadIdx.x;
  if (bid < 3072) {                                  // ---- cast x, one float4/thread ----
    int i = bid * 256 + tid;
    float4 v = ((const float4*)x)[i];
    u16x4 o = { f2bf(v.x), f2bf(v.y), f2bf(v.z), f2bf(v.w) };
    ((u16x4*)xb)[i] = o;
  } else if (bid < 5376) {                           // ---- W(K,N) -> WT(N,K) bf16 ----
    int r = bid - 3072;
    int z = r / 576; r %= 576;
    int kx = r % 24, ny = r / 24;
    const float* W = (z == 0) ? Wq : (z == 1) ? Wk : (z == 2) ? Wv : Wo;
    u16* dst = (z < 3) ? (wqkvT + (size_t)z * DD * DD) : woT;
    int k0 = kx * 32, n0 = ny * 32;
    int tx = tid & 31, ty = tid >> 5;                // 32 x 8
#pragma unroll
    for (int j = 0; j < 4; ++j)
      tile[ty + j * 8][tx] = W[(size_t)(k0 + ty + j * 8) * DD + n0 + tx];
    __syncthreads();
#pragma unroll
    for (int j = 0; j < 4; ++j)
      dst[(size_t)(n0 + ty + j * 8) * DD + k0 + tx] = f2bf(tile[tx][ty + j * 8]);
  } else {                                           // ---- gidx + fused qkv bias ----
    for (int n = tid; n < NQKV; n += 256)
      biasqkv[n] = (n < 768) ? bq[n] : (n < 1536) ? bk[n - 768] : bv[n - 1536];
    if (tid < 64) {                                  // wave 0 only
      int lane = tid;
      if (lane < 32) gidx[lane] = 0;
      int base = 0;
      for (int c0 = 0; c0 < TT; c0 += 64) {
        int mval = gm[c0 + lane];
        unsigned long long bal = __ballot(mval != 0);
        int pre = __popcll(bal & ((1ull << lane) - 1ull));
        if (mval && (base + pre) < 32) gidx[base + pre] = c0 + lane;
        base += __popcll(bal);
        if (base >= 32) break;
      }
    }
  }
}

// ---------------- bf16 MFMA GEMM (qkv): C = A * BT^T + bias, 128x128 tile, bf16 out ----------------
__global__ __launch_bounds__(256) void gemm_qkv(const u16* __restrict__ A, const u16* __restrict__ BT,
                                                const float* __restrict__ bias, u16* __restrict__ C,
                                                int Ndim, int Kd) {
  __shared__ __attribute__((aligned(16))) u16 As[128 * 64];
  __shared__ __attribute__((aligned(16))) u16 Bs[128 * 64];
  const int tid = threadIdx.x;
  const int wave = tid >> 6, lane = tid & 63;
  const int m0 = blockIdx.x * 128, n0 = blockIdx.y * 128;
  const int wm = (wave & 1) << 6, wn = (wave >> 1) << 6;
  const int lr = lane & 15, lk = lane >> 4;
  const int srow_b = lane >> 3;
  const int scol = (lane & 7) * 8;

  f32x4 acc[4][4] = {};

  const int kIters = Kd >> 6;
  for (int kt = 0; kt < kIters; ++kt) {
#pragma unroll
    for (int cc = 0; cc < 4; ++cc) {
      int c = wave * 4 + cc;
      int srow = c * 8 + srow_b;
      async_load16(A + (size_t)(m0 + srow) * Kd + (kt << 6) + scol, (void*)(As + c * 512));
      async_load16(BT + (size_t)(n0 + srow) * Kd + (kt << 6) + scol, (void*)(Bs + c * 512));
    }
    __syncthreads();
#pragma unroll
    for (int kc = 0; kc < 2; ++kc) {
      bf16x8 af[4], bfr[4];
#pragma unroll
      for (int i = 0; i < 4; ++i)
        af[i] = *(const bf16x8*)(As + (wm + i * 16 + lr) * 64 + kc * 32 + lk * 8);
#pragma unroll
      for (int j = 0; j < 4; ++j)
        bfr[j] = *(const bf16x8*)(Bs + (wn + j * 16 + lr) * 64 + kc * 32 + lk * 8);
#pragma unroll
      for (int i = 0; i < 4; ++i)
#pragma unroll
        for (int j = 0; j < 4; ++j)
          acc[i][j] = __builtin_amdgcn_mfma_f32_16x16x32_bf16(af[i], bfr[j], acc[i][j], 0, 0, 0);
    }
    __syncthreads();
  }

#pragma unroll
  for (int i = 0; i < 4; ++i) {
    const int row = m0 + wm + i * 16 + lk * 4;
#pragma unroll
    for (int j = 0; j < 4; ++j) {
      const int col = n0 + wn + j * 16 + lr;
      const float bs = bias[col];
#pragma unroll
      for (int r = 0; r < 4; ++r)
        C[(size_t)(row + r) * Ndim + col] = f2bf(acc[i][j][r] + bs);
    }
  }
}

// ---------------- attention: one block = (b, h, 64 t-rows); emits ctx + compact probs ----------------
__global__ __launch_bounds__(256) void attn_kernel(const u16* __restrict__ qb,
                                                   const int* __restrict__ gidx,
                                                   u16* __restrict__ ctxb,
                                                   float* __restrict__ probsG) {
  __shared__ __attribute__((aligned(16))) u16 Kl[96 * 72];
  __shared__ __attribute__((aligned(16))) u16 Kg[32 * 72];
  __shared__ __attribute__((aligned(16))) u16 Vl[96 * 72];
  __shared__ __attribute__((aligned(16))) u16 Vg[32 * 72];
  __shared__ __attribute__((aligned(16))) float probs[64 * 68];

  const int tid = threadIdx.x;
  const int blk = blockIdx.x;
  const int chunk = blk & 31;
  const int h = (blk >> 5) % NH;
  const int b = blk / 384;
  const int t0 = chunk << 6;

  // ---- phase 1: stage bf16 K/V ----
  {
    const int r = tid >> 3;
    const int c8 = (tid & 7) << 3;
#pragma unroll
    for (int it = 0; it < 3; ++it) {
      int rr = it * 32 + r;
      int t = t0 - 16 + rr;
      t = t < 0 ? 0 : (t > TT - 1 ? TT - 1 : t);
      const u16* src = qb + (size_t)(b * TT + t) * NQKV + h * HDIM + c8;
      *(u16x8*)(Kl + rr * 72 + c8) = *(const u16x8*)(src + 768);
      *(u16x8*)(Vl + rr * 72 + c8) = *(const u16x8*)(src + 1536);
    }
    {
      int t = gidx[r];
      const u16* src = qb + (size_t)(b * TT + t) * NQKV + h * HDIM + c8;
      *(u16x8*)(Kg + r * 72 + c8) = *(const u16x8*)(src + 768);
      *(u16x8*)(Vg + r * 72 + c8) = *(const u16x8*)(src + 1536);
    }
  }
  __syncthreads();

  // ---- phase 2: scores + softmax ----
  const int tl = tid >> 2, sub = tid & 3;
  const int t = t0 + tl;
  const u16* qp = qb + (size_t)(b * TT + t) * NQKV + h * HDIM;
  float qv[64];
#pragma unroll
  for (int i = 0; i < 8; ++i) {
    u16x8 qq = *(const u16x8*)(qp + i * 8);
#pragma unroll
    for (int e = 0; e < 8; ++e) qv[i * 8 + e] = bf2f(qq[e]);
  }

  float sc[17];
  float mmax = -__builtin_inff();
#pragma unroll
  for (int i = 0; i < 17; ++i) {
    const int s = sub + (i << 2);
    const u16* kp;
    bool valid;
    if (s < 33) { kp = Kl + (tl + s) * 72; int j = t - 16 + s; valid = (j >= 0) && (j < TT); }
    else if (s < 65) { kp = Kg + (s - 33) * 72; valid = true; }
    else { kp = Kg; valid = false; }
    float d = 0.f;
#pragma unroll
    for (int i2 = 0; i2 < 8; ++i2) {
      u16x8 kv = *(const u16x8*)(kp + i2 * 8);
#pragma unroll
      for (int e = 0; e < 8; ++e) d += qv[i2 * 8 + e] * bf2f(kv[e]);
    }
    sc[i] = valid ? d * 0.125f : -__builtin_inff();
    mmax = fmaxf(mmax, sc[i]);
  }
  mmax = fmaxf(mmax, __shfl_xor(mmax, 1));
  mmax = fmaxf(mmax, __shfl_xor(mmax, 2));
  float sum = 0.f;
#pragma unroll
  for (int i = 0; i < 17; ++i) { sc[i] = __expf(sc[i] - mmax); sum += sc[i]; }
  sum += __shfl_xor(sum, 1);
  sum += __shfl_xor(sum, 2);
  const float inv = 1.0f / sum;
#pragma unroll
  for (int i = 0; i < 17; ++i) {
    const int s = sub + (i << 2);
    sc[i] *= inv;
    if (s < 65) probs[tl * 68 + s] = sc[i];
  }
  __syncthreads();

  // ---- phase 3: ctx ----
  float cacc[16];
#pragma unroll
  for (int i = 0; i < 16; ++i) cacc[i] = 0.f;
#pragma unroll 1
  for (int k = 0; k < 65; ++k) {
    const float pv = probs[tl * 68 + k];
    const u16* vp = (k < 33) ? (Vl + (tl + k) * 72) : (Vg + (k - 33) * 72);
    const u16* vq = vp + (sub << 4);
    u16x8 v0 = *(const u16x8*)(vq);
    u16x8 v1 = *(const u16x8*)(vq + 8);
#pragma unroll
    for (int e = 0; e < 8; ++e) { cacc[e] += pv * bf2f(v0[e]); cacc[8 + e] += pv * bf2f(v1[e]); }
  }
  {
    u16x8 cb0, cb1;
#pragma unroll
    for (int e = 0; e < 8; ++e) { cb0[e] = f2bf(cacc[e]); cb1[e] = f2bf(cacc[8 + e]); }
    u16* dst = ctxb + (size_t)(b * TT + t) * DD + h * HDIM + (sub << 4);
    *(u16x8*)dst = cb0;
    *(u16x8*)(dst + 8) = cb1;
  }

  // ---- phase 4: dump compact probs rows to global (contiguous, coalesced) ----
  {
    float4* dst = (float4*)(probsG + ((size_t)(b * NH + h) * TT + t0) * 68);
    const float4* srcp = (const float4*)probs;
#pragma unroll 1
    for (int i = tid; i < 1088; i += 256) dst[i] = srcp[i];
  }
}

// ---------------- fused tail: blocks [0,384) = out-projection GEMM; rest = fattn streamer ----------------
// gemm2 blocks at LOW indices: dispatched first, run under the 402 MB write stream.
#define G2_BLOCKS 384
__global__ __launch_bounds__(256) void tail_k(const u16* __restrict__ ctxb, const u16* __restrict__ woT,
                                              const float* __restrict__ bo, float* __restrict__ out,
                                              const float* __restrict__ probsG, const int* __restrict__ gidx,
                                              float* __restrict__ fattn) {
  __shared__ __attribute__((aligned(16))) u16 sA[64 * 64];    // gemm: As | fwrite: Lp(4352B)+gidxs
  __shared__ __attribute__((aligned(16))) u16 sB[128 * 64];
  const int tid = threadIdx.x;
  const int bid = blockIdx.x;

  if (bid < G2_BLOCKS) {
    // ---- out = ctx @ WoT^T + bo : BM=64, BN=128 tile ----
    const int wave = tid >> 6, lane = tid & 63;
    const int m0 = (bid & 63) * 64, n0 = (bid >> 6) * 128;
    const int wn = wave << 5;
    const int lr = lane & 15, lk = lane >> 4;
    const int srow_b = lane >> 3;
    const int scol = (lane & 7) * 8;

    f32x4 acc[4][2] = {};
    for (int kt = 0; kt < DD / 64; ++kt) {
#pragma unroll
      for (int cc = 0; cc < 2; ++cc) {
        int c = wave * 2 + cc;
        int srow = c * 8 + srow_b;
        async_load16(ctxb + (size_t)(m0 + srow) * DD + (kt << 6) + scol, (void*)(sA + c * 512));
      }
#pragma unroll
      for (int cc = 0; cc < 4; ++cc) {
        int c = wave * 4 + cc;
        int srow = c * 8 + srow_b;
        async_load16(woT + (size_t)(n0 + srow) * DD + (kt << 6) + scol, (void*)(sB + c * 512));
      }
      __syncthreads();
#pragma unroll
      for (int kc = 0; kc < 2; ++kc) {
        bf16x8 af[4], bfr[2];
#pragma unroll
        for (int i = 0; i < 4; ++i)
          af[i] = *(const bf16x8*)(sA + (i * 16 + lr) * 64 + kc * 32 + lk * 8);
#pragma unroll
        for (int j = 0; j < 2; ++j)
          bfr[j] = *(const bf16x8*)(sB + (wn + j * 16 + lr) * 64 + kc * 32 + lk * 8);
#pragma unroll
        for (int i = 0; i < 4; ++i)
#pragma unroll
          for (int j = 0; j < 2; ++j)
            acc[i][j] = __builtin_amdgcn_mfma_f32_16x16x32_bf16(af[i], bfr[j], acc[i][j], 0, 0, 0);
      }
      __syncthreads();
    }
#pragma unroll
    for (int i = 0; i < 4; ++i) {
      const int row = m0 + i * 16 + lk * 4;
#pragma unroll
      for (int j = 0; j < 2; ++j) {
        const int col = n0 + wn + j * 16 + lr;
        const float bs = bo[col];
#pragma unroll
        for (int r = 0; r < 4; ++r)
          out[(size_t)(row + r) * DD + col] = acc[i][j][r] + bs;
      }
    }
  } else {
    // ---- fattn streamer: 16 rows per block, band embedded, then global-col overwrite ----
    float* Lp = (float*)sA;                 // 16*68 floats = 4352 B (fits in sA)
    int* gidxs = (int*)sB;
    const int fid = bid - G2_BLOCKS;
    const int slice = fid & 127;
    const int h = (fid >> 7) % NH;
    const int b = fid / (128 * NH);
    const int t0s = slice << 4;

    const float4* src = (const float4*)(probsG + ((size_t)(b * NH + h) * TT + t0s) * 68);
    for (int i = tid; i < 272; i += 256) ((float4*)Lp)[i] = src[i];
    if (tid < 32) gidxs[tid] = gidx[tid];
    __syncthreads();

    float* fbase = fattn + ((size_t)(b * NH + h) * TT + t0s) * TT;
#pragma unroll 1
    for (int it = 0; it < 32; ++it) {
      int q = it * 256 + tid;
      int rl = q >> 9;
      int c4 = (q & 511) << 2;
      int trow = t0s + rl;
      float4 v = make_float4(0.f, 0.f, 0.f, 0.f);
      int kk = c4 - trow + 16;
      if (kk >= -3 && kk < 33) {
        float* vp = &v.x;
#pragma unroll
        for (int e = 0; e < 4; ++e) {
          int k2 = kk + e;
          if ((unsigned)k2 < 33u) vp[e] = Lp[rl * 68 + k2];
        }
      }
      *(float4*)(fbase + (size_t)rl * TT + c4) = v;
    }
    __syncthreads();                  // drain band stores before global-col overwrite
#pragma unroll
    for (int rep = 0; rep < 2; ++rep) {
      int w = rep * 256 + tid;
      int rl = w >> 5, g = w & 31;
      fbase[(size_t)rl * TT + gidxs[g]] = Lp[rl * 68 + 33 + g];
    }
  }
}

extern "C" void kernel_launch(void* const* d_in, const int* in_sizes, int n_in,
                              void* d_out, int out_size, void* d_ws, size_t ws_size,
                              hipStream_t stream) {
  const float* x  = (const float*)d_in[0];
  const int* gm   = (const int*)d_in[1];
  const float* Wq = (const float*)d_in[2];
  const float* bq = (const float*)d_in[3];
  const float* Wk = (const float*)d_in[4];
  const float* bk = (const float*)d_in[5];
  const float* Wv = (const float*)d_in[6];
  const float* bv = (const float*)d_in[7];
  const float* Wo = (const float*)d_in[8];
  const float* bo = (const float*)d_in[9];

  float* out = (float*)d_out;
  float* fattn = out + (size_t)BB * TT * DD;

  char* p = (char*)d_ws;
  u16* xb      = (u16*)p;  p += (size_t)MM * DD * 2;        // 6291456
  u16* wqkvT   = (u16*)p;  p += (size_t)NQKV * DD * 2;      // 3538944
  u16* woT     = (u16*)p;  p += (size_t)DD * DD * 2;        // 1179648
  float* biasq = (float*)p; p += (size_t)NQKV * 4;          // 9216
  int* gidx    = (int*)p;  p += 128;
  u16* qkvb    = (u16*)p;  p += (size_t)MM * NQKV * 2;      // 18874368 (bf16 qkv)
  u16* ctxb    = (u16*)p;  p += (size_t)MM * DD * 2;        // 6291456
  float* probsG= (float*)p; p += (size_t)MM * NH * 68 * 4;  // 13369344

  prep_all<<<5377, 256, 0, stream>>>(x, Wq, Wk, Wv, Wo, gm, bq, bk, bv,
                                     xb, wqkvT, woT, gidx, biasq);
  gemm_qkv<<<dim3(MM / 128, NQKV / 128), 256, 0, stream>>>(xb, wqkvT, biasq, qkvb, NQKV, DD);
  attn_kernel<<<BB * NH * (TT / 64), 256, 0, stream>>>(qkvb, gidx, ctxb, probsG);
  tail_k<<<G2_BLOCKS + BB * NH * (TT / 16), 256, 0, stream>>>(ctxb, woT, bo, out, probsG, gidx, fattn);
}

// Round 10
// 538.045 us; speedup vs baseline: 1.1154x; 1.0015x over previous
//
#include <hip/hip_runtime.h>

typedef unsigned short u16;
typedef __attribute__((ext_vector_type(4))) u16 u16x4;
typedef __attribute__((ext_vector_type(8))) u16 u16x8;
typedef __attribute__((ext_vector_type(8))) short bf16x8;
typedef __attribute__((ext_vector_type(4))) float f32x4;

// Problem constants
#define BB 2
#define TT 2048
#define DD 768
#define NH 12
#define HDIM 64
#define NQKV 2304   // 3*DD
#define MM 4096     // BB*TT

__device__ __forceinline__ u16 f2bf(float f) {
  unsigned u = __float_as_uint(f);
  u += 0x7fffu + ((u >> 16) & 1u);
  return (u16)(u >> 16);
}
__device__ __forceinline__ float bf2f(u16 s) {
  return __uint_as_float(((unsigned)s) << 16);
}
__device__ __forceinline__ void async_load16(const void* g, void* l) {
  __builtin_amdgcn_global_load_lds((const __attribute__((address_space(1))) void*)g,
                                   (__attribute__((address_space(3))) void*)l, 16, 0, 0);
}

// ---------------- merged prep: castx | weight transpose+cast | gidx/bias ----------------
__global__ __launch_bounds__(256) void prep_all(const float* __restrict__ x,
                                                const float* __restrict__ Wq, const float* __restrict__ Wk,
                                                const float* __restrict__ Wv, const float* __restrict__ Wo,
                                                const int* __restrict__ gm,
                                                const float* __restrict__ bq, const float* __restrict__ bk,
                                                const float* __restrict__ bv,
                                                u16* __restrict__ xb, u16* __restrict__ wqkvT,
                                                u16* __restrict__ woT,
                                                int* __restrict__ gidx, float* __restrict__ biasqkv) {
  __shared__ float tile[32][33];
  const int bid = blockIdx.x;
  const int tid = threadIdx.x;
  if (bid < 3072) {                                  // ---- cast x, one float4/thread ----
    int i = bid * 256 + tid;
    float4 v = ((const float4*)x)[i];
    u16x4 o = { f2bf(v.x), f2bf(v.y), f2bf(v.z), f2bf(v.w) };
    ((u16x4*)xb)[i] = o;
  } else if (bid < 5376) {                           // ---- W(K,N) -> WT(N,K) bf16 ----
    int r = bid - 3072;
    int z = r / 576; r %= 576;
    int kx = r % 24, ny = r / 24;
    const float* W = (z == 0) ? Wq : (z == 1) ? Wk : (z == 2) ? Wv : Wo;
    u16* dst = (z < 3) ? (wqkvT + (size_t)z * DD * DD) : woT;
    int k0 = kx * 32, n0 = ny * 32;
    int tx = tid & 31, ty = tid >> 5;                // 32 x 8
#pragma unroll
    for (int j = 0; j < 4; ++j)
      tile[ty + j * 8][tx] = W[(size_t)(k0 + ty + j * 8) * DD + n0 + tx];
    __syncthreads();
#pragma unroll
    for (int j = 0; j < 4; ++j)
      dst[(size_t)(n0 + ty + j * 8) * DD + k0 + tx] = f2bf(tile[tx][ty + j * 8]);
  } else {                                           // ---- gidx + fused qkv bias ----
    for (int n = tid; n < NQKV; n += 256)
      biasqkv[n] = (n < 768) ? bq[n] : (n < 1536) ? bk[n - 768] : bv[n - 1536];
    if (tid < 64) {                                  // wave 0 only
      int lane = tid;
      if (lane < 32) gidx[lane] = 0;
      int base = 0;
      for (int c0 = 0; c0 < TT; c0 += 64) {
        int mval = gm[c0 + lane];
        unsigned long long bal = __ballot(mval != 0);
        int pre = __popcll(bal & ((1ull << lane) - 1ull));
        if (mval && (base + pre) < 32) gidx[base + pre] = c0 + lane;
        base += __popcll(bal);
        if (base >= 32) break;
      }
    }
  }
}

// ---------------- bf16 MFMA GEMM (qkv): C = A * BT^T + bias, 128x128 tile, bf16 out ----------------
__global__ __launch_bounds__(256) void gemm_qkv(const u16* __restrict__ A, const u16* __restrict__ BT,
                                                const float* __restrict__ bias, u16* __restrict__ C,
                                                int Ndim, int Kd) {
  __shared__ __attribute__((aligned(16))) u16 As[128 * 64];
  __shared__ __attribute__((aligned(16))) u16 Bs[128 * 64];
  const int tid = threadIdx.x;
  const int wave = tid >> 6, lane = tid & 63;
  const int m0 = blockIdx.x * 128, n0 = blockIdx.y * 128;
  const int wm = (wave & 1) << 6, wn = (wave >> 1) << 6;
  const int lr = lane & 15, lk = lane >> 4;
  const int srow_b = lane >> 3;
  const int scol = (lane & 7) * 8;

  f32x4 acc[4][4] = {};

  const int kIters = Kd >> 6;
  for (int kt = 0; kt < kIters; ++kt) {
#pragma unroll
    for (int cc = 0; cc < 4; ++cc) {
      int c = wave * 4 + cc;
      int srow = c * 8 + srow_b;
      async_load16(A + (size_t)(m0 + srow) * Kd + (kt << 6) + scol, (void*)(As + c * 512));
      async_load16(BT + (size_t)(n0 + srow) * Kd + (kt << 6) + scol, (void*)(Bs + c * 512));
    }
    __syncthreads();
#pragma unroll
    for (int kc = 0; kc < 2; ++kc) {
      bf16x8 af[4], bfr[4];
#pragma unroll
      for (int i = 0; i < 4; ++i)
        af[i] = *(const bf16x8*)(As + (wm + i * 16 + lr) * 64 + kc * 32 + lk * 8);
#pragma unroll
      for (int j = 0; j < 4; ++j)
        bfr[j] = *(const bf16x8*)(Bs + (wn + j * 16 + lr) * 64 + kc * 32 + lk * 8);
#pragma unroll
      for (int i = 0; i < 4; ++i)
#pragma unroll
        for (int j = 0; j < 4; ++j)
          acc[i][j] = __builtin_amdgcn_mfma_f32_16x16x32_bf16(af[i], bfr[j], acc[i][j], 0, 0, 0);
    }
    __syncthreads();
  }

#pragma unroll
  for (int i = 0; i < 4; ++i) {
    const int row = m0 + wm + i * 16 + lk * 4;
#pragma unroll
    for (int j = 0; j < 4; ++j) {
      const int col = n0 + wn + j * 16 + lr;
      const float bs = bias[col];
#pragma unroll
      for (int r = 0; r < 4; ++r)
        C[(size_t)(row + r) * Ndim + col] = f2bf(acc[i][j][r] + bs);
    }
  }
}

// ---------------- attention: one block = (b, h, 64 t-rows); emits ctx + compact probs ----------------
// q kept PACKED bf16 in registers (32 VGPRs vs 64) to get natural occupancy 3 blocks/CU.
__global__ __launch_bounds__(256) void attn_kernel(const u16* __restrict__ qb,
                                                   const int* __restrict__ gidx,
                                                   u16* __restrict__ ctxb,
                                                   float* __restrict__ probsG) {
  __shared__ __attribute__((aligned(16))) u16 Kl[96 * 72];
  __shared__ __attribute__((aligned(16))) u16 Kg[32 * 72];
  __shared__ __attribute__((aligned(16))) u16 Vl[96 * 72];
  __shared__ __attribute__((aligned(16))) u16 Vg[32 * 72];
  __shared__ __attribute__((aligned(16))) float probs[64 * 68];

  const int tid = threadIdx.x;
  const int blk = blockIdx.x;
  const int chunk = blk & 31;
  const int h = (blk >> 5) % NH;
  const int b = blk / 384;
  const int t0 = chunk << 6;

  // ---- phase 1: stage bf16 K/V ----
  {
    const int r = tid >> 3;
    const int c8 = (tid & 7) << 3;
#pragma unroll
    for (int it = 0; it < 3; ++it) {
      int rr = it * 32 + r;
      int t = t0 - 16 + rr;
      t = t < 0 ? 0 : (t > TT - 1 ? TT - 1 : t);
      const u16* src = qb + (size_t)(b * TT + t) * NQKV + h * HDIM + c8;
      *(u16x8*)(Kl + rr * 72 + c8) = *(const u16x8*)(src + 768);
      *(u16x8*)(Vl + rr * 72 + c8) = *(const u16x8*)(src + 1536);
    }
    {
      int t = gidx[r];
      const u16* src = qb + (size_t)(b * TT + t) * NQKV + h * HDIM + c8;
      *(u16x8*)(Kg + r * 72 + c8) = *(const u16x8*)(src + 768);
      *(u16x8*)(Vg + r * 72 + c8) = *(const u16x8*)(src + 1536);
    }
  }
  __syncthreads();

  // ---- phase 2: scores + softmax. quad (4 threads) per t-row, scores strided by 4 ----
  const int tl = tid >> 2, sub = tid & 3;
  const int t = t0 + tl;
  const u16* qp = qb + (size_t)(b * TT + t) * NQKV + h * HDIM;
  u16x8 qpk[8];                       // q packed bf16: 32 VGPRs
#pragma unroll
  for (int i = 0; i < 8; ++i) qpk[i] = *(const u16x8*)(qp + i * 8);

  float sc[17];
  float mmax = -__builtin_inff();
#pragma unroll
  for (int i = 0; i < 17; ++i) {
    const int s = sub + (i << 2);
    const u16* kp;
    bool valid;
    if (s < 33) { kp = Kl + (tl + s) * 72; int j = t - 16 + s; valid = (j >= 0) && (j < TT); }
    else if (s < 65) { kp = Kg + (s - 33) * 72; valid = true; }
    else { kp = Kg; valid = false; }
    float d = 0.f;
#pragma unroll
    for (int i2 = 0; i2 < 8; ++i2) {
      u16x8 kv = *(const u16x8*)(kp + i2 * 8);
      u16x8 qq = qpk[i2];
#pragma unroll
      for (int e = 0; e < 8; ++e) d += bf2f(qq[e]) * bf2f(kv[e]);
    }
    sc[i] = valid ? d * 0.125f : -__builtin_inff();
    mmax = fmaxf(mmax, sc[i]);
  }
  mmax = fmaxf(mmax, __shfl_xor(mmax, 1));
  mmax = fmaxf(mmax, __shfl_xor(mmax, 2));
  float sum = 0.f;
#pragma unroll
  for (int i = 0; i < 17; ++i) { sc[i] = __expf(sc[i] - mmax); sum += sc[i]; }
  sum += __shfl_xor(sum, 1);
  sum += __shfl_xor(sum, 2);
  const float inv = 1.0f / sum;
#pragma unroll
  for (int i = 0; i < 17; ++i) {
    const int s = sub + (i << 2);
    sc[i] *= inv;
    if (s < 65) probs[tl * 68 + s] = sc[i];
  }
  __syncthreads();

  // ---- phase 3: ctx ----
  float cacc[16];
#pragma unroll
  for (int i = 0; i < 16; ++i) cacc[i] = 0.f;
#pragma unroll 1
  for (int k = 0; k < 65; ++k) {
    const float pv = probs[tl * 68 + k];
    const u16* vp = (k < 33) ? (Vl + (tl + k) * 72) : (Vg + (k - 33) * 72);
    const u16* vq = vp + (sub << 4);
    u16x8 v0 = *(const u16x8*)(vq);
    u16x8 v1 = *(const u16x8*)(vq + 8);
#pragma unroll
    for (int e = 0; e < 8; ++e) { cacc[e] += pv * bf2f(v0[e]); cacc[8 + e] += pv * bf2f(v1[e]); }
  }
  {
    u16x8 cb0, cb1;
#pragma unroll
    for (int e = 0; e < 8; ++e) { cb0[e] = f2bf(cacc[e]); cb1[e] = f2bf(cacc[8 + e]); }
    u16* dst = ctxb + (size_t)(b * TT + t) * DD + h * HDIM + (sub << 4);
    *(u16x8*)dst = cb0;
    *(u16x8*)(dst + 8) = cb1;
  }

  // ---- phase 4: dump compact probs rows to global (contiguous, coalesced) ----
  {
    float4* dst = (float4*)(probsG + ((size_t)(b * NH + h) * TT + t0) * 68);
    const float4* srcp = (const float4*)probs;
#pragma unroll 1
    for (int i = tid; i < 1088; i += 256) dst[i] = srcp[i];
  }
}

// ---------------- fused tail: blocks [0,384) = out-projection GEMM; rest = fattn streamer ----------------
#define G2_BLOCKS 384
__global__ __launch_bounds__(256) void tail_k(const u16* __restrict__ ctxb, const u16* __restrict__ woT,
                                              const float* __restrict__ bo, float* __restrict__ out,
                                              const float* __restrict__ probsG, const int* __restrict__ gidx,
                                              float* __restrict__ fattn) {
  __shared__ __attribute__((aligned(16))) u16 sA[64 * 64];    // gemm: As | fwrite: Lp(4352B)+gidxs
  __shared__ __attribute__((aligned(16))) u16 sB[128 * 64];
  const int tid = threadIdx.x;
  const int bid = blockIdx.x;

  if (bid < G2_BLOCKS) {
    // ---- out = ctx @ WoT^T + bo : BM=64, BN=128 tile ----
    const int wave = tid >> 6, lane = tid & 63;
    const int m0 = (bid & 63) * 64, n0 = (bid >> 6) * 128;
    const int wn = wave << 5;
    const int lr = lane & 15, lk = lane >> 4;
    const int srow_b = lane >> 3;
    const int scol = (lane & 7) * 8;

    f32x4 acc[4][2] = {};
    for (int kt = 0; kt < DD / 64; ++kt) {
#pragma unroll
      for (int cc = 0; cc < 2; ++cc) {
        int c = wave * 2 + cc;
        int srow = c * 8 + srow_b;
        async_load16(ctxb + (size_t)(m0 + srow) * DD + (kt << 6) + scol, (void*)(sA + c * 512));
      }
#pragma unroll
      for (int cc = 0; cc < 4; ++cc) {
        int c = wave * 4 + cc;
        int srow = c * 8 + srow_b;
        async_load16(woT + (size_t)(n0 + srow) * DD + (kt << 6) + scol, (void*)(sB + c * 512));
      }
      __syncthreads();
#pragma unroll
      for (int kc = 0; kc < 2; ++kc) {
        bf16x8 af[4], bfr[2];
#pragma unroll
        for (int i = 0; i < 4; ++i)
          af[i] = *(const bf16x8*)(sA + (i * 16 + lr) * 64 + kc * 32 + lk * 8);
#pragma unroll
        for (int j = 0; j < 2; ++j)
          bfr[j] = *(const bf16x8*)(sB + (wn + j * 16 + lr) * 64 + kc * 32 + lk * 8);
#pragma unroll
        for (int i = 0; i < 4; ++i)
#pragma unroll
          for (int j = 0; j < 2; ++j)
            acc[i][j] = __builtin_amdgcn_mfma_f32_16x16x32_bf16(af[i], bfr[j], acc[i][j], 0, 0, 0);
      }
      __syncthreads();
    }
#pragma unroll
    for (int i = 0; i < 4; ++i) {
      const int row = m0 + i * 16 + lk * 4;
#pragma unroll
      for (int j = 0; j < 2; ++j) {
        const int col = n0 + wn + j * 16 + lr;
        const float bs = bo[col];
#pragma unroll
        for (int r = 0; r < 4; ++r)
          out[(size_t)(row + r) * DD + col] = acc[i][j][r] + bs;
      }
    }
  } else {
    // ---- fattn streamer: 16 rows per block, band embedded, then global-col overwrite ----
    float* Lp = (float*)sA;                 // 16*68 floats = 4352 B (fits in sA)
    int* gidxs = (int*)sB;
    const int fid = bid - G2_BLOCKS;
    const int slice = fid & 127;
    const int h = (fid >> 7) % NH;
    const int b = fid / (128 * NH);
    const int t0s = slice << 4;

    const float4* src = (const float4*)(probsG + ((size_t)(b * NH + h) * TT + t0s) * 68);
    for (int i = tid; i < 272; i += 256) ((float4*)Lp)[i] = src[i];
    if (tid < 32) gidxs[tid] = gidx[tid];
    __syncthreads();

    float* fbase = fattn + ((size_t)(b * NH + h) * TT + t0s) * TT;
#pragma unroll 1
    for (int it = 0; it < 32; ++it) {
      int q = it * 256 + tid;
      int rl = q >> 9;
      int c4 = (q & 511) << 2;
      int trow = t0s + rl;
      float4 v = make_float4(0.f, 0.f, 0.f, 0.f);
      int kk = c4 - trow + 16;
      if (kk >= -3 && kk < 33) {
        float* vp = &v.x;
#pragma unroll
        for (int e = 0; e < 4; ++e) {
          int k2 = kk + e;
          if ((unsigned)k2 < 33u) vp[e] = Lp[rl * 68 + k2];
        }
      }
      *(float4*)(fbase + (size_t)rl * TT + c4) = v;
    }
    __syncthreads();                  // drain band stores before global-col overwrite
#pragma unroll
    for (int rep = 0; rep < 2; ++rep) {
      int w = rep * 256 + tid;
      int rl = w >> 5, g = w & 31;
      fbase[(size_t)rl * TT + gidxs[g]] = Lp[rl * 68 + 33 + g];
    }
  }
}

extern "C" void kernel_launch(void* const* d_in, const int* in_sizes, int n_in,
                              void* d_out, int out_size, void* d_ws, size_t ws_size,
                              hipStream_t stream) {
  const float* x  = (const float*)d_in[0];
  const int* gm   = (const int*)d_in[1];
  const float* Wq = (const float*)d_in[2];
  const float* bq = (const float*)d_in[3];
  const float* Wk = (const float*)d_in[4];
  const float* bk = (const float*)d_in[5];
  const float* Wv = (const float*)d_in[6];
  const float* bv = (const float*)d_in[7];
  const float* Wo = (const float*)d_in[8];
  const float* bo = (const float*)d_in[9];

  float* out = (float*)d_out;
  float* fattn = out + (size_t)BB * TT * DD;

  char* p = (char*)d_ws;
  u16* xb      = (u16*)p;  p += (size_t)MM * DD * 2;        // 6291456
  u16* wqkvT   = (u16*)p;  p += (size_t)NQKV * DD * 2;      // 3538944
  u16* woT     = (u16*)p;  p += (size_t)DD * DD * 2;        // 1179648
  float* biasq = (float*)p; p += (size_t)NQKV * 4;          // 9216
  int* gidx    = (int*)p;  p += 128;
  u16* qkvb    = (u16*)p;  p += (size_t)MM * NQKV * 2;      // 18874368 (bf16 qkv)
  u16* ctxb    = (u16*)p;  p += (size_t)MM * DD * 2;        // 6291456
  float* probsG= (float*)p; p += (size_t)MM * NH * 68 * 4;  // 13369344

  prep_all<<<5377, 256, 0, stream>>>(x, Wq, Wk, Wv, Wo, gm, bq, bk, bv,
                                     xb, wqkvT, woT, gidx, biasq);
  gemm_qkv<<<dim3(MM / 128, NQKV / 128), 256, 0, stream>>>(xb, wqkvT, biasq, qkvb, NQKV, DD);
  attn_kernel<<<BB * NH * (TT / 64), 256, 0, stream>>>(qkvb, gidx, ctxb, probsG);
  tail_k<<<G2_BLOCKS + BB * NH * (TT / 16), 256, 0, stream>>>(ctxb, woT, bo, out, probsG, gidx, fattn);
}